// Round 7
// baseline (665.968 us; speedup 1.0000x reference)
//
#include <hip/hip_runtime.h>

// GAT fused pipeline, fp16 MFMA (16x16x32), MI355X gfx950.
// B=16, N=1024, F_in=F_out=256, H=8, ALPHA=0.2
//
// Round-13: R11 (512thr, reg spill) and R12 (1024thr, 1 blk/CU lockstep)
// both refuted the "L2 traffic" theory -- halved Bp traffic, FETCH
// unchanged, perf WORSE. The lever is cross-block overlap of the per-chunk
// vmcnt drain. So: revert to the proven R10 pv geometry (98us) and stack
// the two validated micro-wins:
//  - lsum-in-P-gen (validated R12, absmax identical): removes ones-MFMA
//    (-11% MFMA), accl regs, doL divergence. l = shfl_xor(1) fold.
//  - 3 blocks/CU: lns overlaid on dead-by-epilogue ejs -> LDS 53264B
//    (x3 = 156KB < 160); VGPR ~108 < 170 cap. launch_bounds(256,3).
// R10 reference: pv 98us, Mfma 30%, VALU 39%, occ 20%, conflicts 0.
//
// ws: [0,64MB) WhT fp16 [B][H][F_out][N]; +67108864 eiP[2][128K] f32;
//     +68157440 ejP[2][128K] f32. Total 66 MiB.

#define L2E 1.442695041f

typedef _Float16 half8 __attribute__((ext_vector_type(8)));
typedef __fp16 fp16x2 __attribute__((ext_vector_type(2)));
typedef float floatx4 __attribute__((ext_vector_type(4)));

#if __has_builtin(__builtin_amdgcn_exp2f)
#define EXP2F(x) __builtin_amdgcn_exp2f(x)
#else
#define EXP2F(x) exp2f(x)
#endif

#if __has_builtin(__builtin_amdgcn_rcpf)
#define RCPF(x) __builtin_amdgcn_rcpf(x)
#else
#define RCPF(x) (1.0f / (x))
#endif

static __device__ inline unsigned int pack2(float a, float b) {
    fp16x2 h = __builtin_amdgcn_cvt_pkrtz(a, b);
    return __builtin_bit_cast(unsigned int, h);
}

typedef __attribute__((address_space(1))) const void GV;
typedef __attribute__((address_space(3))) void LV;
static __device__ inline void load_lds16(const void* g, void* l) {
    __builtin_amdgcn_global_load_lds((GV*)g, (LV*)l, 16, 0, 0);
}

// 64B-row swizzle (wh tiles): chunk c of 16B, c' = c ^ ((row>>1)&3)
static __device__ inline int swz(int row, int c) {
    return (row << 6) + ((((c) ^ (row >> 1)) & 3) << 4);
}
// 128B-row swizzle (pv tiles): 8 chunks of 16B, c' = c ^ (row&7)
static __device__ inline int swz128(int row, int c) {
    return (row << 7) + ((((c) ^ row) & 7) << 4);
}

// ---------------------------------------------------------------------------
// Stage 1: WhT[b,h,o,n] = sum_f W[h,o,f]*h[b,n,f] + bW[h,o]  (fp16 out)
// + per-ot ei/ej partial epilogue. Tile 128(o) x 128(bn), K=256, BK=32.
// (unchanged from round-10)
__global__ __launch_bounds__(256, 3) void wh_kernel(
    const float* __restrict__ hin, const float* __restrict__ W,
    const float* __restrict__ bW, _Float16* __restrict__ WhT,
    const float* __restrict__ a1, const float* __restrict__ a2,
    float* __restrict__ eiP, float* __restrict__ ejP)
{
    const int bnt  = blockIdx.x;   // 0..127
    const int ot   = blockIdx.y;   // 0..1
    const int head = blockIdx.z;   // 0..7
    const int t    = threadIdx.x;
    const int wave = t >> 6, lane = t & 63;
    const int l15 = lane & 15, quad = lane >> 4;
    const int wmh = wave & 1, wnh = wave >> 1;

    __shared__ char smem[16384];
    _Float16* As = (_Float16*)smem;            // 128 rows x 64B = 8192
    _Float16* Bs = (_Float16*)(smem + 8192);   // 128 rows x 64B = 8192
    // epilogue overlay (tiles dead after K-loop):
    float* bWs   = (float*)smem;               // 128 f32
    float* a1s   = (float*)(smem + 512);
    float* a2s   = (float*)(smem + 1024);
    float* part1 = (float*)(smem + 1536);      // [2 wmh][128 row] = 1KB
    float* part2 = (float*)(smem + 2560);      // 1KB

    const int o0 = ot * 128;
    const int bn0 = bnt * 128;
    floatx4 acc[4][4];
#pragma unroll
    for (int a = 0; a < 4; a++)
#pragma unroll
        for (int b = 0; b < 4; b++) acc[a][b] = (floatx4)0.0f;

    const int ar = t >> 1, ah = t & 1;   // staging: row, 16-float half
    const float* Wrow = W + (size_t)(head * 256 + o0 + ar) * 256 + ah * 16;
    const float* hrow = hin + (size_t)(bn0 + ar) * 256 + ah * 16;

    float4 pa0, pa1, pa2, pa3, pb0, pb1, pb2, pb3;
    {
        const float4* p4 = (const float4*)Wrow;
        pa0 = p4[0]; pa1 = p4[1]; pa2 = p4[2]; pa3 = p4[3];
        const float4* q4 = (const float4*)hrow;
        pb0 = q4[0]; pb1 = q4[1]; pb2 = q4[2]; pb3 = q4[3];
    }

    for (int f0 = 0; f0 < 256; f0 += 32) {
        __syncthreads();
        *(uint4*)((char*)As + swz(ar, 2 * ah)) =
            make_uint4(pack2(pa0.x, pa0.y), pack2(pa0.z, pa0.w),
                       pack2(pa1.x, pa1.y), pack2(pa1.z, pa1.w));
        *(uint4*)((char*)As + swz(ar, 2 * ah + 1)) =
            make_uint4(pack2(pa2.x, pa2.y), pack2(pa2.z, pa2.w),
                       pack2(pa3.x, pa3.y), pack2(pa3.z, pa3.w));
        *(uint4*)((char*)Bs + swz(ar, 2 * ah)) =
            make_uint4(pack2(pb0.x, pb0.y), pack2(pb0.z, pb0.w),
                       pack2(pb1.x, pb1.y), pack2(pb1.z, pb1.w));
        *(uint4*)((char*)Bs + swz(ar, 2 * ah + 1)) =
            make_uint4(pack2(pb2.x, pb2.y), pack2(pb2.z, pb2.w),
                       pack2(pb3.x, pb3.y), pack2(pb3.z, pb3.w));
        if (f0 < 224) {   // prefetch next chunk
            const float4* p4 = (const float4*)(Wrow + f0 + 32);
            pa0 = p4[0]; pa1 = p4[1]; pa2 = p4[2]; pa3 = p4[3];
            const float4* q4 = (const float4*)(hrow + f0 + 32);
            pb0 = q4[0]; pb1 = q4[1]; pb2 = q4[2]; pb3 = q4[3];
        }
        __syncthreads();
        half8 af[4], bf[4];
#pragma unroll
        for (int a = 0; a < 4; a++)
            af[a] = *(const half8*)((char*)As + swz(wmh * 64 + a * 16 + l15, quad));
#pragma unroll
        for (int b = 0; b < 4; b++)
            bf[b] = *(const half8*)((char*)Bs + swz(wnh * 64 + b * 16 + l15, quad));
#pragma unroll
        for (int a = 0; a < 4; a++)
#pragma unroll
            for (int b = 0; b < 4; b++)
                acc[a][b] = __builtin_amdgcn_mfma_f32_16x16x32_f16(af[a], bf[b], acc[a][b], 0, 0, 0);
    }

    __syncthreads();   // tiles dead; overlay epilogue arrays
    if (t < 128) {
        bWs[t] = bW[head * 256 + o0 + t];
        a1s[t] = a1[head * 256 + o0 + t];
        a2s[t] = a2[head * 256 + o0 + t];
    }
    __syncthreads();

    const int bidx = bn0 >> 10;     // batch index (tile never crosses batch)
    const int nbase = bn0 & 1023;
#pragma unroll
    for (int b = 0; b < 4; b++) {
        const int bnl = wnh * 64 + b * 16 + l15;   // local bn 0..127
        const int n = nbase + bnl;
        float p1 = 0.f, p2 = 0.f;
#pragma unroll
        for (int a = 0; a < 4; a++) {
#pragma unroll
            for (int r = 0; r < 4; r++) {
                int ol = wmh * 64 + a * 16 + quad * 4 + r;   // local o
                float v = acc[a][b][r] + bWs[ol];
                WhT[(((size_t)(bidx * 8 + head) * 256 + o0 + ol) << 10) + n] = (_Float16)v;
                p1 = fmaf(v, a1s[ol], p1);
                p2 = fmaf(v, a2s[ol], p2);
            }
        }
        p1 += __shfl_xor(p1, 16, 64); p1 += __shfl_xor(p1, 32, 64);
        p2 += __shfl_xor(p2, 16, 64); p2 += __shfl_xor(p2, 32, 64);
        if (lane < 16) {
            part1[wmh * 128 + bnl] = p1;
            part2[wmh * 128 + bnl] = p2;
        }
    }
    __syncthreads();
    if (t < 128) {
        float s1 = part1[t] + part1[128 + t];
        float s2 = part2[t] + part2[128 + t];
        const size_t idx = (size_t)(bidx * 8 + head) * 1024 + nbase + t;
        eiP[(size_t)ot * 131072 + idx] = s1;
        ejP[(size_t)ot * 131072 + idx] = s2;
    }
}

// ---------------------------------------------------------------------------
// Stage 2: out[b,i,h*256+o] = sigmoid(relu( (1/l_i) * sum_j p~_ij * Wh[j,o] ))
// p~ = exp2(max(Ac+ej', fma(.2,ej',Bc))); l_i summed during P-gen (no
// ones-MFMA). Tile 128(i) x 256(o), K=1024 in BK=64, 256 thr = 4 waves:
// wmh = wave&1 over i (64), wnh = wave>>1 over o (128), acc[4][8]/wave.
// B staged via global_load_lds (pre-swizzled source, linear LDS dest).
// LDS 53264B -> 3 blocks/CU (cross-block overlap hides the vmcnt drain).
__global__ __launch_bounds__(256, 3) void pv_kernel(
    const _Float16* __restrict__ WhT, const float* __restrict__ eiP,
    const float* __restrict__ ejP, const float* __restrict__ bA,
    float* __restrict__ out)
{
    const int bh = blockIdx.x;   // 0..127 (fast dim -> XCD key; all 8 it
                                 //  blocks of one bh land on XCD bh%8)
    const int it = blockIdx.y;   // 0..7
    const int b = bh >> 3, head = bh & 7;
    const int t = threadIdx.x;
    const int wave = t >> 6, lane = t & 63;
    const int l15 = lane & 15, quad = lane >> 4;
    const int wmh = wave & 1, wnh = wave >> 1;

    __shared__ char smem[53264];
    _Float16* Ap = (_Float16*)smem;             // P: 128 rows x 128B = 16384
    _Float16* Bp = (_Float16*)(smem + 16384);   // WhT: 256 rows x 128B = 32768
    float* ejs  = (float*)(smem + 49152);       // 1024 f32 (*L2E) 4KB
    float* wred = (float*)(smem + 53248);       // 4 wave maxes (16B)
    float* lns  = (float*)(smem + 49152);       // overlay: ejs dead at epilogue

    // preamble: ej = ej0+ej1 (ot halves), stage *L2E, block max
    const float* ej0 = ejP + bh * 1024;
    const float* ej1 = ejP + 131072 + bh * 1024;
    float mx = -1e30f;
#pragma unroll
    for (int k = 0; k < 4; k++) {
        int idx = t + k * 256;
        float v = (ej0[idx] + ej1[idx]) * L2E;
        ejs[idx] = v;
        mx = fmaxf(mx, v);
    }
#pragma unroll
    for (int m = 32; m; m >>= 1) mx = fmaxf(mx, __shfl_xor(mx, m, 64));
    if (lane == 0) wred[wave] = mx;
    __syncthreads();
    float ejmax = fmaxf(fmaxf(wred[0], wred[1]), fmaxf(wred[2], wred[3]));

    const int i0 = it * 128;
    const int prow = t >> 1, pjh = t & 1;   // P-gen: row, 32-j half
    const float cip = (eiP[bh * 1024 + i0 + prow] +
                       eiP[131072 + bh * 1024 + i0 + prow] + bA[head]) * L2E;
    const float tmv = cip + ejmax;
    const float nm = -fmaxf(tmv, 0.2f * tmv);   // -m*log2e
    const float Ac = cip + nm;                  // folds nm into both branches
    const float Bc = fmaf(0.2f, cip, nm);       // max(e,.2e)+nm = max(Ac+ev, .2ev+Bc)

    // B staging via global_load_lds: wave w covers o-rows [w*64, w*64+64).
    // LDS dest is linear (HW writes lane*16); source address pre-swizzled so
    // LDS position cp holds chunk cp^(row&7)  -> read side uses swz128.
    // row&7 == lane>>3 for every call (q*8 and w*64 are 0 mod 8).
    const int rsub = lane >> 3, cp7 = lane & 7;
    const _Float16* bsrc = WhT + ((size_t)bh << 18)
                         + ((size_t)(wave * 64 + rsub) << 10)
                         + ((cp7 ^ rsub) << 3);
    char* bdst0 = (char*)Bp + wave * 8192;

    floatx4 acc[4][8];
#pragma unroll
    for (int a = 0; a < 4; a++)
#pragma unroll
        for (int c = 0; c < 8; c++) acc[a][c] = (floatx4)0.0f;
    float lsum = 0.0f;

    for (int j0 = 0; j0 < 1024; j0 += 64) {
        __syncthreads();
        // issue B loads first: P-gen's exp VALU stretch hides DMA latency
#pragma unroll
        for (int q = 0; q < 8; q++)
            load_lds16(bsrc + j0 + q * 8192, bdst0 + q * 1024);
        {   // P-gen: 32 exps -> 4 swizzled uint4; accumulate lsum
            const float4* ejp4 = (const float4*)(ejs + j0 + pjh * 32);
#pragma unroll
            for (int q = 0; q < 4; q++) {
                float4 e4a = ejp4[2 * q], e4b = ejp4[2 * q + 1];
                float p[8];
                const float ev[8] = {e4a.x, e4a.y, e4a.z, e4a.w,
                                     e4b.x, e4b.y, e4b.z, e4b.w};
#pragma unroll
                for (int u = 0; u < 8; u++) {
                    float t1 = Ac + ev[u];
                    float t2 = fmaf(0.2f, ev[u], Bc);
                    p[u] = EXP2F(fmaxf(t1, t2));
                    lsum += p[u];
                }
                *(uint4*)((char*)Ap + swz128(prow, pjh * 4 + q)) =
                    make_uint4(pack2(p[0], p[1]), pack2(p[2], p[3]),
                               pack2(p[4], p[5]), pack2(p[6], p[7]));
            }
        }
        __syncthreads();   // drains vmcnt (global_load_lds) + lgkm (Ap writes)
#pragma unroll
        for (int kk = 0; kk < 2; kk++) {
            half8 af[4], bf[8];
#pragma unroll
            for (int a = 0; a < 4; a++)
                af[a] = *(const half8*)((char*)Ap + swz128(wmh * 64 + a * 16 + l15, kk * 4 + quad));
#pragma unroll
            for (int c = 0; c < 8; c++)
                bf[c] = *(const half8*)((char*)Bp + swz128(wnh * 128 + c * 16 + l15, kk * 4 + quad));
#pragma unroll
            for (int a = 0; a < 4; a++)
#pragma unroll
                for (int c = 0; c < 8; c++)
                    acc[a][c] = __builtin_amdgcn_mfma_f32_16x16x32_f16(af[a], bf[c], acc[a][c], 0, 0, 0);
        }
    }

    // fold the 2 per-row P-gen threads' partial sums (adjacent lanes)
    lsum += __shfl_xor(lsum, 1, 64);
    __syncthreads();          // all ejs reads done; safe to overlay lns
    if (pjh == 0) lns[prow] = lsum;
    __syncthreads();

    // rs = -L2E / l  (raw v_rcp; rel err ~1e-5 << tolerance)
    float rs[4][4];
#pragma unroll
    for (int a = 0; a < 4; a++)
#pragma unroll
        for (int r = 0; r < 4; r++)
            rs[a][r] = -L2E * RCPF(lns[wmh * 64 + a * 16 + quad * 4 + r]);

#pragma unroll
    for (int a = 0; a < 4; a++) {
#pragma unroll
        for (int c = 0; c < 8; c++) {
            int o = wnh * 128 + c * 16 + l15;
#pragma unroll
            for (int r = 0; r < 4; r++) {
                int i = i0 + wmh * 64 + a * 16 + quad * 4 + r;
                // sigmoid(relu(v)) = rcp(1 + exp2(min(v*(-L2E/l), 0)))
                float tx = fminf(acc[a][c][r] * rs[a][r], 0.0f);
                float y = RCPF(1.0f + EXP2F(tx));
                out[((size_t)(b * 1024 + i) << 11) + head * 256 + o] = y;
            }
        }
    }
}

// ---------------------------------------------------------------------------
extern "C" void kernel_launch(void* const* d_in, const int* in_sizes, int n_in,
                              void* d_out, int out_size, void* d_ws, size_t ws_size,
                              hipStream_t stream)
{
    const float* h  = (const float*)d_in[0];
    const float* W  = (const float*)d_in[1];
    const float* bW = (const float*)d_in[2];
    const float* a1 = (const float*)d_in[3];
    const float* a2 = (const float*)d_in[4];
    const float* bA = (const float*)d_in[5];
    float* out = (float*)d_out;

    char* ws = (char*)d_ws;
    _Float16* WhT = (_Float16*)ws;                       // 67108864 B
    float* eiP = (float*)(ws + 67108864);                // 2 x 524288 B
    float* ejP = (float*)(ws + 67108864 + 1048576);      // 2 x 524288 B

    hipLaunchKernelGGL(wh_kernel, dim3(128, 2, 8), dim3(256), 0, stream,
                       h, W, bW, WhT, a1, a2, eiP, ejP);
    hipLaunchKernelGGL(pv_kernel, dim3(128, 8), dim3(256), 0, stream,
                       WhT, eiP, ejP, bA, out);
}

// Round 8
// 277.779 us; speedup vs baseline: 2.3975x; 2.3975x over previous
//
#include <hip/hip_runtime.h>

// GAT fused pipeline, fp16 MFMA (16x16x32), MI355X gfx950.
// B=16, N=1024, F_in=F_out=256, H=8, ALPHA=0.2
//
// Round-14: R13 spilled like R11 (VGPR_Count=84 < 128-reg acc -> scratch,
// 479MB FETCH). LESSON: reported VGPR_Count (124) excludes the unified-file
// accumulator side; true pv footprint ~250 regs -> 2 blocks/CU is a HARD
// cap for the 128i x 256o tile. R9 (pipeline), R11/R13 (occupancy) all
// refuted: R10 structure is the local optimum. This round = R10 verbatim
// + the one validated micro-win (R12, absmax-identical):
//  - lsum-in-P-gen: drop ones-MFMA (-11% MFMA/K-step), accl regs, doL
//    divergence. l_i = shfl_xor(lsum,1) fold (2 P-gen threads per row).
// Everything else byte-identical to R10 (98us pv): launch_bounds(256,2),
// BK=64, issue-DMA-first, pre-swizzled global_load_lds, same smem map.
//
// ws: [0,64MB) WhT fp16 [B][H][F_out][N]; +67108864 eiP[2][128K] f32;
//     +68157440 ejP[2][128K] f32. Total 66 MiB.

#define L2E 1.442695041f

typedef _Float16 half8 __attribute__((ext_vector_type(8)));
typedef __fp16 fp16x2 __attribute__((ext_vector_type(2)));
typedef float floatx4 __attribute__((ext_vector_type(4)));

#if __has_builtin(__builtin_amdgcn_exp2f)
#define EXP2F(x) __builtin_amdgcn_exp2f(x)
#else
#define EXP2F(x) exp2f(x)
#endif

#if __has_builtin(__builtin_amdgcn_rcpf)
#define RCPF(x) __builtin_amdgcn_rcpf(x)
#else
#define RCPF(x) (1.0f / (x))
#endif

static __device__ inline unsigned int pack2(float a, float b) {
    fp16x2 h = __builtin_amdgcn_cvt_pkrtz(a, b);
    return __builtin_bit_cast(unsigned int, h);
}

typedef __attribute__((address_space(1))) const void GV;
typedef __attribute__((address_space(3))) void LV;
static __device__ inline void load_lds16(const void* g, void* l) {
    __builtin_amdgcn_global_load_lds((GV*)g, (LV*)l, 16, 0, 0);
}

// 64B-row swizzle (wh tiles): chunk c of 16B, c' = c ^ ((row>>1)&3)
static __device__ inline int swz(int row, int c) {
    return (row << 6) + ((((c) ^ (row >> 1)) & 3) << 4);
}
// 128B-row swizzle (pv tiles): 8 chunks of 16B, c' = c ^ (row&7)
static __device__ inline int swz128(int row, int c) {
    return (row << 7) + ((((c) ^ row) & 7) << 4);
}

// ---------------------------------------------------------------------------
// Stage 1: WhT[b,h,o,n] = sum_f W[h,o,f]*h[b,n,f] + bW[h,o]  (fp16 out)
// + per-ot ei/ej partial epilogue. Tile 128(o) x 128(bn), K=256, BK=32.
// (unchanged from round-10)
__global__ __launch_bounds__(256, 3) void wh_kernel(
    const float* __restrict__ hin, const float* __restrict__ W,
    const float* __restrict__ bW, _Float16* __restrict__ WhT,
    const float* __restrict__ a1, const float* __restrict__ a2,
    float* __restrict__ eiP, float* __restrict__ ejP)
{
    const int bnt  = blockIdx.x;   // 0..127
    const int ot   = blockIdx.y;   // 0..1
    const int head = blockIdx.z;   // 0..7
    const int t    = threadIdx.x;
    const int wave = t >> 6, lane = t & 63;
    const int l15 = lane & 15, quad = lane >> 4;
    const int wmh = wave & 1, wnh = wave >> 1;

    __shared__ char smem[16384];
    _Float16* As = (_Float16*)smem;            // 128 rows x 64B = 8192
    _Float16* Bs = (_Float16*)(smem + 8192);   // 128 rows x 64B = 8192
    // epilogue overlay (tiles dead after K-loop):
    float* bWs   = (float*)smem;               // 128 f32
    float* a1s   = (float*)(smem + 512);
    float* a2s   = (float*)(smem + 1024);
    float* part1 = (float*)(smem + 1536);      // [2 wmh][128 row] = 1KB
    float* part2 = (float*)(smem + 2560);      // 1KB

    const int o0 = ot * 128;
    const int bn0 = bnt * 128;
    floatx4 acc[4][4];
#pragma unroll
    for (int a = 0; a < 4; a++)
#pragma unroll
        for (int b = 0; b < 4; b++) acc[a][b] = (floatx4)0.0f;

    const int ar = t >> 1, ah = t & 1;   // staging: row, 16-float half
    const float* Wrow = W + (size_t)(head * 256 + o0 + ar) * 256 + ah * 16;
    const float* hrow = hin + (size_t)(bn0 + ar) * 256 + ah * 16;

    float4 pa0, pa1, pa2, pa3, pb0, pb1, pb2, pb3;
    {
        const float4* p4 = (const float4*)Wrow;
        pa0 = p4[0]; pa1 = p4[1]; pa2 = p4[2]; pa3 = p4[3];
        const float4* q4 = (const float4*)hrow;
        pb0 = q4[0]; pb1 = q4[1]; pb2 = q4[2]; pb3 = q4[3];
    }

    for (int f0 = 0; f0 < 256; f0 += 32) {
        __syncthreads();
        *(uint4*)((char*)As + swz(ar, 2 * ah)) =
            make_uint4(pack2(pa0.x, pa0.y), pack2(pa0.z, pa0.w),
                       pack2(pa1.x, pa1.y), pack2(pa1.z, pa1.w));
        *(uint4*)((char*)As + swz(ar, 2 * ah + 1)) =
            make_uint4(pack2(pa2.x, pa2.y), pack2(pa2.z, pa2.w),
                       pack2(pa3.x, pa3.y), pack2(pa3.z, pa3.w));
        *(uint4*)((char*)Bs + swz(ar, 2 * ah)) =
            make_uint4(pack2(pb0.x, pb0.y), pack2(pb0.z, pb0.w),
                       pack2(pb1.x, pb1.y), pack2(pb1.z, pb1.w));
        *(uint4*)((char*)Bs + swz(ar, 2 * ah + 1)) =
            make_uint4(pack2(pb2.x, pb2.y), pack2(pb2.z, pb2.w),
                       pack2(pb3.x, pb3.y), pack2(pb3.z, pb3.w));
        if (f0 < 224) {   // prefetch next chunk
            const float4* p4 = (const float4*)(Wrow + f0 + 32);
            pa0 = p4[0]; pa1 = p4[1]; pa2 = p4[2]; pa3 = p4[3];
            const float4* q4 = (const float4*)(hrow + f0 + 32);
            pb0 = q4[0]; pb1 = q4[1]; pb2 = q4[2]; pb3 = q4[3];
        }
        __syncthreads();
        half8 af[4], bf[4];
#pragma unroll
        for (int a = 0; a < 4; a++)
            af[a] = *(const half8*)((char*)As + swz(wmh * 64 + a * 16 + l15, quad));
#pragma unroll
        for (int b = 0; b < 4; b++)
            bf[b] = *(const half8*)((char*)Bs + swz(wnh * 64 + b * 16 + l15, quad));
#pragma unroll
        for (int a = 0; a < 4; a++)
#pragma unroll
            for (int b = 0; b < 4; b++)
                acc[a][b] = __builtin_amdgcn_mfma_f32_16x16x32_f16(af[a], bf[b], acc[a][b], 0, 0, 0);
    }

    __syncthreads();   // tiles dead; overlay epilogue arrays
    if (t < 128) {
        bWs[t] = bW[head * 256 + o0 + t];
        a1s[t] = a1[head * 256 + o0 + t];
        a2s[t] = a2[head * 256 + o0 + t];
    }
    __syncthreads();

    const int bidx = bn0 >> 10;     // batch index (tile never crosses batch)
    const int nbase = bn0 & 1023;
#pragma unroll
    for (int b = 0; b < 4; b++) {
        const int bnl = wnh * 64 + b * 16 + l15;   // local bn 0..127
        const int n = nbase + bnl;
        float p1 = 0.f, p2 = 0.f;
#pragma unroll
        for (int a = 0; a < 4; a++) {
#pragma unroll
            for (int r = 0; r < 4; r++) {
                int ol = wmh * 64 + a * 16 + quad * 4 + r;   // local o
                float v = acc[a][b][r] + bWs[ol];
                WhT[(((size_t)(bidx * 8 + head) * 256 + o0 + ol) << 10) + n] = (_Float16)v;
                p1 = fmaf(v, a1s[ol], p1);
                p2 = fmaf(v, a2s[ol], p2);
            }
        }
        p1 += __shfl_xor(p1, 16, 64); p1 += __shfl_xor(p1, 32, 64);
        p2 += __shfl_xor(p2, 16, 64); p2 += __shfl_xor(p2, 32, 64);
        if (lane < 16) {
            part1[wmh * 128 + bnl] = p1;
            part2[wmh * 128 + bnl] = p2;
        }
    }
    __syncthreads();
    if (t < 128) {
        float s1 = part1[t] + part1[128 + t];
        float s2 = part2[t] + part2[128 + t];
        const size_t idx = (size_t)(bidx * 8 + head) * 1024 + nbase + t;
        eiP[(size_t)ot * 131072 + idx] = s1;
        ejP[(size_t)ot * 131072 + idx] = s2;
    }
}

// ---------------------------------------------------------------------------
// Stage 2: out[b,i,h*256+o] = sigmoid(relu( (1/l_i) * sum_j p~_ij * Wh[j,o] ))
// p~ = exp2(max(Ac+ej', fma(.2,ej',Bc))); l_i summed during P-gen (no
// ones-MFMA; validated R12, absmax identical).
// Tile 128(i) x 256(o), K=1024 in BK=64, 256 thr = 4 waves:
// wmh = wave&1 over i (64), wnh = wave>>1 over o (128), acc[4][8]/wave.
// B staged via global_load_lds (pre-swizzled source, linear LDS dest).
// launch_bounds(256,2): 2 blocks/CU is the HARD cap for this tile
// (acc[4][8]=128 unified-file regs on top of ~124 arch VGPRs; R11/R13
// proved 3 blocks/CU spills the accumulator).
__global__ __launch_bounds__(256, 2) void pv_kernel(
    const _Float16* __restrict__ WhT, const float* __restrict__ eiP,
    const float* __restrict__ ejP, const float* __restrict__ bA,
    float* __restrict__ out)
{
    const int bh = blockIdx.x;   // 0..127 (fast dim -> XCD key; all 8 it
                                 //  blocks of one bh land on XCD bh%8)
    const int it = blockIdx.y;   // 0..7
    const int b = bh >> 3, head = bh & 7;
    const int t = threadIdx.x;
    const int wave = t >> 6, lane = t & 63;
    const int l15 = lane & 15, quad = lane >> 4;
    const int wmh = wave & 1, wnh = wave >> 1;

    __shared__ char smem[53776];
    _Float16* Ap = (_Float16*)smem;             // P: 128 rows x 128B = 16384
    _Float16* Bp = (_Float16*)(smem + 16384);   // WhT: 256 rows x 128B = 32768
    float* ejs  = (float*)(smem + 49152);       // 1024 f32 (*L2E) 4KB
    float* lns  = (float*)(smem + 53248);       // 128 denominators
    float* wred = (float*)(smem + 53760);       // 4 wave maxes

    // preamble: ej = ej0+ej1 (ot halves), stage *L2E, block max
    const float* ej0 = ejP + bh * 1024;
    const float* ej1 = ejP + 131072 + bh * 1024;
    float mx = -1e30f;
#pragma unroll
    for (int k = 0; k < 4; k++) {
        int idx = t + k * 256;
        float v = (ej0[idx] + ej1[idx]) * L2E;
        ejs[idx] = v;
        mx = fmaxf(mx, v);
    }
#pragma unroll
    for (int m = 32; m; m >>= 1) mx = fmaxf(mx, __shfl_xor(mx, m, 64));
    if (lane == 0) wred[wave] = mx;
    __syncthreads();
    float ejmax = fmaxf(fmaxf(wred[0], wred[1]), fmaxf(wred[2], wred[3]));

    const int i0 = it * 128;
    const int prow = t >> 1, pjh = t & 1;   // P-gen: row, 32-j half
    const float cip = (eiP[bh * 1024 + i0 + prow] +
                       eiP[131072 + bh * 1024 + i0 + prow] + bA[head]) * L2E;
    const float tmv = cip + ejmax;
    const float nm = -fmaxf(tmv, 0.2f * tmv);   // -m*log2e
    const float Ac = cip + nm;                  // folds nm into both branches
    const float Bc = fmaf(0.2f, cip, nm);       // max(e,.2e)+nm = max(Ac+ev, .2ev+Bc)

    // B staging via global_load_lds: wave w covers o-rows [w*64, w*64+64).
    // LDS dest is linear (HW writes lane*16); source address pre-swizzled so
    // LDS position cp holds chunk cp^(row&7)  -> read side uses swz128.
    // row&7 == lane>>3 for every call (q*8 and w*64 are 0 mod 8).
    const int rsub = lane >> 3, cp7 = lane & 7;
    const _Float16* bsrc = WhT + ((size_t)bh << 18)
                         + ((size_t)(wave * 64 + rsub) << 10)
                         + ((cp7 ^ rsub) << 3);
    char* bdst0 = (char*)Bp + wave * 8192;

    floatx4 acc[4][8];
#pragma unroll
    for (int a = 0; a < 4; a++)
#pragma unroll
        for (int c = 0; c < 8; c++) acc[a][c] = (floatx4)0.0f;
    float lsum = 0.0f;

    for (int j0 = 0; j0 < 1024; j0 += 64) {
        __syncthreads();
        // issue B loads first: P-gen's exp VALU stretch hides DMA latency
#pragma unroll
        for (int q = 0; q < 8; q++)
            load_lds16(bsrc + j0 + q * 8192, bdst0 + q * 1024);
        {   // P-gen: 32 exps -> 4 swizzled uint4; accumulate lsum
            const float4* ejp4 = (const float4*)(ejs + j0 + pjh * 32);
#pragma unroll
            for (int q = 0; q < 4; q++) {
                float4 e4a = ejp4[2 * q], e4b = ejp4[2 * q + 1];
                float p[8];
                const float ev[8] = {e4a.x, e4a.y, e4a.z, e4a.w,
                                     e4b.x, e4b.y, e4b.z, e4b.w};
#pragma unroll
                for (int u = 0; u < 8; u++) {
                    float t1 = Ac + ev[u];
                    float t2 = fmaf(0.2f, ev[u], Bc);
                    p[u] = EXP2F(fmaxf(t1, t2));
                    lsum += p[u];
                }
                *(uint4*)((char*)Ap + swz128(prow, pjh * 4 + q)) =
                    make_uint4(pack2(p[0], p[1]), pack2(p[2], p[3]),
                               pack2(p[4], p[5]), pack2(p[6], p[7]));
            }
        }
        __syncthreads();   // drains vmcnt (global_load_lds) + lgkm (Ap writes)
#pragma unroll
        for (int kk = 0; kk < 2; kk++) {
            half8 af[4], bf[8];
#pragma unroll
            for (int a = 0; a < 4; a++)
                af[a] = *(const half8*)((char*)Ap + swz128(wmh * 64 + a * 16 + l15, kk * 4 + quad));
#pragma unroll
            for (int c = 0; c < 8; c++)
                bf[c] = *(const half8*)((char*)Bp + swz128(wnh * 128 + c * 16 + l15, kk * 4 + quad));
#pragma unroll
            for (int a = 0; a < 4; a++)
#pragma unroll
                for (int c = 0; c < 8; c++)
                    acc[a][c] = __builtin_amdgcn_mfma_f32_16x16x32_f16(af[a], bf[c], acc[a][c], 0, 0, 0);
        }
    }

    // denominator: fold the 2 per-row P-gen threads (adjacent lanes), then
    // publish to lns (own region, no overlay hazard) and sync once.
    lsum += __shfl_xor(lsum, 1, 64);
    if (pjh == 0) lns[prow] = lsum;
    __syncthreads();

    // rs = -L2E / l  (raw v_rcp; rel err ~1e-5 << tolerance)
    float rs[4][4];
#pragma unroll
    for (int a = 0; a < 4; a++)
#pragma unroll
        for (int r = 0; r < 4; r++)
            rs[a][r] = -L2E * RCPF(lns[wmh * 64 + a * 16 + quad * 4 + r]);

#pragma unroll
    for (int a = 0; a < 4; a++) {
#pragma unroll
        for (int c = 0; c < 8; c++) {
            int o = wnh * 128 + c * 16 + l15;
#pragma unroll
            for (int r = 0; r < 4; r++) {
                int i = i0 + wmh * 64 + a * 16 + quad * 4 + r;
                // sigmoid(relu(v)) = rcp(1 + exp2(min(v*(-L2E/l), 0)))
                float tx = fminf(acc[a][c][r] * rs[a][r], 0.0f);
                float y = RCPF(1.0f + EXP2F(tx));
                out[((size_t)(b * 1024 + i) << 11) + head * 256 + o] = y;
            }
        }
    }
}

// ---------------------------------------------------------------------------
extern "C" void kernel_launch(void* const* d_in, const int* in_sizes, int n_in,
                              void* d_out, int out_size, void* d_ws, size_t ws_size,
                              hipStream_t stream)
{
    const float* h  = (const float*)d_in[0];
    const float* W  = (const float*)d_in[1];
    const float* bW = (const float*)d_in[2];
    const float* a1 = (const float*)d_in[3];
    const float* a2 = (const float*)d_in[4];
    const float* bA = (const float*)d_in[5];
    float* out = (float*)d_out;

    char* ws = (char*)d_ws;
    _Float16* WhT = (_Float16*)ws;                       // 67108864 B
    float* eiP = (float*)(ws + 67108864);                // 2 x 524288 B
    float* ejP = (float*)(ws + 67108864 + 1048576);      // 2 x 524288 B

    hipLaunchKernelGGL(wh_kernel, dim3(128, 2, 8), dim3(256), 0, stream,
                       h, W, bW, WhT, a1, a2, eiP, ejP);
    hipLaunchKernelGGL(pv_kernel, dim3(128, 8), dim3(256), 0, stream,
                       WhT, eiP, ejP, bA, out);
}